// Round 7
// baseline (228.792 us; speedup 1.0000x reference)
//
#include <hip/hip_runtime.h>
#include <hip/hip_bf16.h>

#define S 512
#define KEEP 64
#define SPARSITY 0.125f
#define SLOPE 5.0f

// Geometry: example is [B=64, C=8, H=512, S=512] f32.
#define ROW4 128            // float4 per row (S/4)
#define ROWS_PER_BATCH 4096 // C*H
#define BLOCKS_PER_BATCH 32
#define ROWS_PER_BLOCK 128  // ROWS_PER_BATCH / BLOCKS_PER_BATCH
#define BATCH4 524288       // ROWS_PER_BATCH * ROW4

typedef float vf4 __attribute__((ext_vector_type(4)));

// Fully fused: each block (b, chunk) recomputes the 512-wide top-64 mask for
// its batch b (redundant across the 32 blocks of a batch, ~2us of VALU+LDS),
// then streams its 512 KB slice with NT loads/stores (R3 structure, best
// measured). The first NT load cluster is issued BEFORE the mask phase so the
// mask compute hides under the first loads' HBM latency. Saves the separate
// mask dispatch + inter-kernel graph dependency gap.
__global__ __launch_bounds__(256) void loupe_fused_kernel(
    const vf4* __restrict__ ex,
    const float* __restrict__ weight,
    const float* __restrict__ thresh,
    vf4* __restrict__ out) {
    __shared__ vf4 xv4[S / 4];     // sigmoid values, then scores (in-place)
    __shared__ float red[S];       // mean-reduction scratch
    __shared__ float msk[S];       // binary mask row

    float* xv = (float*)xv4;

    const int b     = blockIdx.x >> 5;          // / BLOCKS_PER_BATCH
    const int chunk = blockIdx.x & 31;
    const int t     = threadIdx.x;
    const int s4    = t & 127;
    const int rowo  = t >> 7;                    // 0 or 1

    const vf4* src = ex  + b * BATCH4 + (chunk * ROWS_PER_BLOCK + rowo) * ROW4 + s4;
    vf4*       dst = out + b * BATCH4 + (chunk * ROWS_PER_BLOCK + rowo) * ROW4 + s4;

    // ---- issue first NT load cluster (in flight during mask phase) ----
    vf4 e[8];
    #pragma unroll
    for (int u = 0; u < 8; ++u)
        e[u] = __builtin_nontemporal_load(src + u * 2 * ROW4);

    // ---- mask row for batch b; thread t owns columns t and t+256 ----
    const float w0  = weight[t];
    const float w1  = weight[t + 256];
    const float th0 = thresh[b * S + t];
    const float th1 = thresh[b * S + t + 256];

    // Numerically-stable sigmoid, matching jax.nn.sigmoid.
    const float z0 = SLOPE * w0;
    const float z1 = SLOPE * w1;
    const float q0 = expf(-fabsf(z0));
    const float q1 = expf(-fabsf(z1));
    const float x0 = (z0 >= 0.0f) ? (1.0f / (1.0f + q0)) : (q0 / (1.0f + q0));
    const float x1 = (z1 >= 0.0f) ? (1.0f / (1.0f + q1)) : (q1 / (1.0f + q1));

    red[t]       = x0;
    red[t + 256] = x1;
    __syncthreads();
    // 512-wide tree reduce, identical op order to the verified 2-kernel version.
    #pragma unroll
    for (int off = 256; off > 0; off >>= 1) {
        if (t < off) red[t] += red[t + off];
        __syncthreads();
    }
    const float xbar = red[0] * (1.0f / (float)S);

    float pm0, pm1;
    if (xbar > SPARSITY) {
        pm0 = x0 * SPARSITY / xbar;
        pm1 = x1 * SPARSITY / xbar;
    } else {
        pm0 = 1.0f - (1.0f - x0) * (1.0f - SPARSITY) / (1.0f - xbar);
        pm1 = 1.0f - (1.0f - x1) * (1.0f - SPARSITY) / (1.0f - xbar);
    }
    const float sc0 = pm0 - th0;
    const float sc1 = pm1 - th1;
    xv[t]       = sc0;
    xv[t + 256] = sc1;
    __syncthreads();

    // Exact rank (ties -> lowest index, matching lax.top_k); float4 LDS reads,
    // broadcast across lanes (conflict-free).
    int r0 = 0, r1 = 0;
    #pragma unroll 4
    for (int j4 = 0; j4 < S / 4; ++j4) {
        const vf4 o4 = xv4[j4];
        #pragma unroll
        for (int c = 0; c < 4; ++c) {
            const float o = o4[c];
            const int j = 4 * j4 + c;
            r0 += (o > sc0) || (o == sc0 && j < t);
            r1 += (o > sc1) || (o == sc1 && j < (t + 256));
        }
    }
    msk[t]       = (r0 < KEEP) ? 1.0f : 0.0f;
    msk[t + 256] = (r1 < KEEP) ? 1.0f : 0.0f;
    __syncthreads();

    vf4 m;
    m.x = msk[4 * s4 + 0];
    m.y = msk[4 * s4 + 1];
    m.z = msk[4 * s4 + 2];
    m.w = msk[4 * s4 + 3];

    // ---- streaming multiply (R3 structure: NT both, depth-8 clusters) ----
    #pragma unroll
    for (int u = 0; u < 8; ++u)
        __builtin_nontemporal_store(e[u] * m, dst + u * 2 * ROW4);
    src += 16 * ROW4;
    dst += 16 * ROW4;

    #pragma unroll
    for (int g = 1; g < 8; ++g) {
        #pragma unroll
        for (int u = 0; u < 8; ++u)
            e[u] = __builtin_nontemporal_load(src + u * 2 * ROW4);
        #pragma unroll
        for (int u = 0; u < 8; ++u)
            __builtin_nontemporal_store(e[u] * m, dst + u * 2 * ROW4);
        src += 16 * ROW4;
        dst += 16 * ROW4;
    }
}

extern "C" void kernel_launch(void* const* d_in, const int* in_sizes, int n_in,
                              void* d_out, int out_size, void* d_ws, size_t ws_size,
                              hipStream_t stream) {
    const float* example = (const float*)d_in[0];   // [64, 8, 512, 512]
    const float* weight  = (const float*)d_in[1];   // [512]
    const float* thresh  = (const float*)d_in[2];   // [64, 512]
    float* out = (float*)d_out;

    const int B = in_sizes[2] / S;                  // 64

    loupe_fused_kernel<<<B * BLOCKS_PER_BATCH, 256, 0, stream>>>(
        (const vf4*)example, weight, thresh, (vf4*)out);
}

// Round 9
// 211.327 us; speedup vs baseline: 1.0826x; 1.0826x over previous
//
#include <hip/hip_runtime.h>
#include <hip/hip_bf16.h>

#define S 512
#define KEEP 64
#define SPARSITY 0.125f
#define SLOPE 5.0f

// Geometry: example is [B=64, C=8, H=512, S=512] f32.
#define ROW4 128            // float4 per row (S/4)
#define ROWS_PER_BATCH 4096 // C*H
#define BLOCKS_PER_BATCH 32
#define ROWS_PER_BLOCK 128  // ROWS_PER_BATCH / BLOCKS_PER_BATCH
#define BATCH4 524288       // ROWS_PER_BATCH * ROW4

typedef float vf4 __attribute__((ext_vector_type(4)));

// One block per batch row b. 512 threads, one per frequency line s.
// Exact top-64 via rank counting (ties -> lowest index, matching lax.top_k).
__global__ __launch_bounds__(512) void loupe_mask_kernel(
    const float* __restrict__ weight,
    const float* __restrict__ thresh,
    float* __restrict__ mask) {
    __shared__ float red[S];
    __shared__ float sc[S];

    const int b = blockIdx.x;
    const int s = threadIdx.x;

    // Numerically-stable sigmoid, matching jax.nn.sigmoid.
    const float z = SLOPE * weight[s];
    const float e = expf(-fabsf(z));
    const float x = (z >= 0.0f) ? (1.0f / (1.0f + e)) : (e / (1.0f + e));

    red[s] = x;
    __syncthreads();
    #pragma unroll
    for (int off = S / 2; off > 0; off >>= 1) {
        if (s < off) red[s] += red[s + off];
        __syncthreads();
    }
    const float xbar = red[0] * (1.0f / (float)S);

    float pm;
    if (xbar > SPARSITY) {
        pm = x * SPARSITY / xbar;
    } else {
        pm = 1.0f - (1.0f - x) * (1.0f - SPARSITY) / (1.0f - xbar);
    }

    const float score = pm - thresh[b * S + s];
    sc[s] = score;
    __syncthreads();

    int rank = 0;
    #pragma unroll 8
    for (int j = 0; j < S; ++j) {
        const float o = sc[j];
        rank += (o > score) || (o == score && j < s);
    }
    mask[b * S + s] = (rank < KEEP) ? 1.0f : 0.0f;
}

// Streaming multiply, register-resident mask, explicit 8-deep load batching,
// non-temporal loads/stores (measured best: R3 = 207.8 us, ~5.3 TB/s mixed).
// NO control dependency on the mask (R8 lesson: gating loads on exact-zero
// mask compares broke graph-replay determinism).
__global__ __launch_bounds__(256) void loupe_apply_kernel(
    const vf4* __restrict__ ex,
    const vf4* __restrict__ mask4,   // [B][ROW4]
    vf4* __restrict__ out) {
    const int b     = blockIdx.x >> 5;          // / BLOCKS_PER_BATCH
    const int chunk = blockIdx.x & 31;
    const int t     = threadIdx.x;
    const int s4    = t & 127;
    const int rowo  = t >> 7;                    // 0 or 1

    const vf4 m = mask4[b * ROW4 + s4];          // loaded once, L2-hit

    const vf4* src = ex  + b * BATCH4 + (chunk * ROWS_PER_BLOCK + rowo) * ROW4 + s4;
    vf4*       dst = out + b * BATCH4 + (chunk * ROWS_PER_BLOCK + rowo) * ROW4 + s4;

    #pragma unroll
    for (int g = 0; g < 8; ++g) {
        vf4 e[8];
        #pragma unroll
        for (int u = 0; u < 8; ++u)
            e[u] = __builtin_nontemporal_load(src + u * 2 * ROW4);
        #pragma unroll
        for (int u = 0; u < 8; ++u)
            __builtin_nontemporal_store(e[u] * m, dst + u * 2 * ROW4);
        src += 16 * ROW4;
        dst += 16 * ROW4;
    }
}

extern "C" void kernel_launch(void* const* d_in, const int* in_sizes, int n_in,
                              void* d_out, int out_size, void* d_ws, size_t ws_size,
                              hipStream_t stream) {
    const float* example = (const float*)d_in[0];   // [64, 8, 512, 512]
    const float* weight  = (const float*)d_in[1];   // [512]
    const float* thresh  = (const float*)d_in[2];   // [64, 512]
    float* out  = (float*)d_out;
    float* mask = (float*)d_ws;                     // [64, 512] floats = 128 KB

    const int B = in_sizes[2] / S;                  // 64

    loupe_mask_kernel<<<B, S, 0, stream>>>(weight, thresh, mask);

    loupe_apply_kernel<<<B * BLOCKS_PER_BATCH, 256, 0, stream>>>(
        (const vf4*)example, (const vf4*)mask, (vf4*)out);
}